// Round 1
// baseline (14364.807 us; speedup 1.0000x reference)
//
#include <hip/hip_runtime.h>
#include <hip/hip_bf16.h>

typedef _Float16 half8 __attribute__((ext_vector_type(8)));
typedef float f32x4 __attribute__((ext_vector_type(4)));

#define T_SEQ 512
#define NBATCH 32
#define HID 512
#define OUT_H_OFF 16777216   // 32*512*1024
#define OUT_HC_STRIDE 65536  // 4*32*512

__device__ __forceinline__ float sigf(float x) { return 1.0f / (1.0f + __expf(-x)); }
__device__ __forceinline__ float tanhf_(float x) {
    float e = __expf(-2.0f * fabsf(x));
    float t = (1.0f - e) / (1.0f + e);
    return copysignf(t, x);
}

// ---------- prep kernels ----------
__global__ void k_cast(const float* __restrict__ s, _Float16* __restrict__ d, int n4) {
    int i = blockIdx.x * 256 + threadIdx.x;
    if (i < n4) {
        float4 v = ((const float4*)s)[i];
        _Float16 o0 = (_Float16)v.x, o1 = (_Float16)v.y, o2 = (_Float16)v.z, o3 = (_Float16)v.w;
        half8* dummy; (void)dummy;
        _Float16* p = d + (size_t)i * 4;
        p[0] = o0; p[1] = o1; p[2] = o2; p[3] = o3;
    }
}

// X [32][512][512] fp32 -> Xh [t*32+b][512] fp16
__global__ void k_cast_x(const float* __restrict__ X, _Float16* __restrict__ Xh) {
    int i = blockIdx.x * 256 + threadIdx.x;     // 2,097,152 threads
    int d = (i & 127) * 4;
    int rb = i >> 7;                            // t*32+b
    int b = rb & 31, t = rb >> 5;
    float4 v = *(const float4*)(X + ((size_t)b * 512 + t) * 512 + d);
    _Float16* p = Xh + (size_t)rb * 512 + d;
    p[0] = (_Float16)v.x; p[1] = (_Float16)v.y; p[2] = (_Float16)v.z; p[3] = (_Float16)v.w;
}

__global__ void k_bias(const float* __restrict__ a0, const float* __restrict__ b0,
                       const float* __restrict__ a1, const float* __restrict__ b1,
                       const float* __restrict__ a2, const float* __restrict__ b2,
                       const float* __restrict__ a3, const float* __restrict__ b3,
                       float* __restrict__ out0, float* __restrict__ out1) {
    int g = blockIdx.x * 256 + threadIdx.x;  // 0..8191
    int j = g & 2047;
    int pair = g >> 11;  // 0: l0 fwd, 1: l0 rev, 2: l1 fwd, 3: l1 rev
    const float *pa, *pb;
    switch (pair) {
        case 0: pa = a0; pb = b0; break;
        case 1: pa = a1; pb = b1; break;
        case 2: pa = a2; pb = b2; break;
        default: pa = a3; pb = b3; break;
    }
    float v = pa[j] + pb[j];
    if (g < 4096) out0[g] = v; else out1[g - 4096] = v;
}

// ---------- GEMM: C[M x 4096] = A[M x K] * W[4096 x K]^T + bias, fp16 in, fp16 out ----------
__global__ __launch_bounds__(256) void k_gemm(const _Float16* __restrict__ A,
                                              const _Float16* __restrict__ W,
                                              const float* __restrict__ bias,
                                              _Float16* __restrict__ C, int K) {
    __shared__ _Float16 As[128][72];
    __shared__ _Float16 Bs[128][72];
    const int tid = threadIdx.x;
    const int lane = tid & 63, wave = tid >> 6;
    const int ln = lane & 15, q = lane >> 4;
    const int wm = wave >> 1, wn = wave & 1;
    const int bm = blockIdx.y, bn = blockIdx.x;

    f32x4 acc[4][4] = {};
    const int kIters = K >> 6;
    for (int kt = 0; kt < kIters; ++kt) {
        const int k0 = kt << 6;
#pragma unroll
        for (int i = 0; i < 4; ++i) {
            int c = tid + i * 256;
            int row = c >> 3, kc = c & 7;
            *(half8*)&As[row][kc * 8] = *(const half8*)(A + (size_t)(bm * 128 + row) * K + k0 + kc * 8);
            *(half8*)&Bs[row][kc * 8] = *(const half8*)(W + (size_t)(bn * 128 + row) * K + k0 + kc * 8);
        }
        __syncthreads();
#pragma unroll
        for (int ks = 0; ks < 2; ++ks) {
            half8 a[4], b[4];
#pragma unroll
            for (int mi = 0; mi < 4; ++mi) a[mi] = *(const half8*)&As[wm * 64 + mi * 16 + ln][ks * 32 + q * 8];
#pragma unroll
            for (int ni = 0; ni < 4; ++ni) b[ni] = *(const half8*)&Bs[wn * 64 + ni * 16 + ln][ks * 32 + q * 8];
#pragma unroll
            for (int mi = 0; mi < 4; ++mi)
#pragma unroll
                for (int ni = 0; ni < 4; ++ni)
                    acc[mi][ni] = __builtin_amdgcn_mfma_f32_16x16x32_f16(a[mi], b[ni], acc[mi][ni], 0, 0, 0);
        }
        __syncthreads();
    }
#pragma unroll
    for (int ni = 0; ni < 4; ++ni) {
        int col = bn * 128 + wn * 64 + ni * 16 + ln;
        float bv = bias[col];
#pragma unroll
        for (int mi = 0; mi < 4; ++mi) {
            int row = bm * 128 + wm * 64 + mi * 16 + q * 4;
#pragma unroll
            for (int r = 0; r < 4; ++r) {
                C[(size_t)(row + r) * 4096 + col] = (_Float16)(acc[mi][ni][r] + bv);
            }
        }
    }
}

// ---------- persistent recurrence kernel ----------
// grid = 64 blocks: blockIdx 0..31 fwd (dir 0), 32..63 rev (dir 1). Each block owns
// j-slice [j0, j0+16) across all 4 gates. c-state lives in registers; h exchanged
// via double-buffered global hbuf with a device-scope barrier each step.
template <int LAYER>
__global__ __launch_bounds__(256, 1) void k_rec(const _Float16* __restrict__ gx,    // [T*32][4096]
                                                const _Float16* __restrict__ Whh,   // [4096][512]
                                                _Float16* __restrict__ hbuf,        // [2][2][32][512]
                                                _Float16* __restrict__ hs_out,      // L0: [T][32][1024]
                                                float* __restrict__ out,
                                                unsigned* __restrict__ bar) {
    __shared__ _Float16 h_s[32][520];
    __shared__ float gbuf[4][32][17];
    const int tid = threadIdx.x;
    const int lane = tid & 63, wave = tid >> 6;  // wave == gate index (0:i 1:f 2:g 3:o)
    const int ln = lane & 15, q = lane >> 4;
    const int dir = blockIdx.x >> 5, jb = blockIdx.x & 31, j0 = jb * 16;

    // preload W_hh fragments for this wave's 16 gate-rows: 16 k-steps, held in VGPRs
    half8 wfrag[16];
    {
        const _Float16* wrow = Whh + (size_t)(dir * 2048 + wave * 512 + j0 + ln) * 512 + q * 8;
#pragma unroll
        for (int ks = 0; ks < 16; ++ks) wfrag[ks] = *(const half8*)(wrow + ks * 32);
    }
    float c0 = 0.f, c1 = 0.f;
    const int jj = tid & 15, bb = tid >> 4;

    for (int s = 0; s < 512; ++s) {
        const int t = dir ? (511 - s) : s;
        // gx scalars for the elementwise stage (independent of barrier -> issue early)
        float gxv[2][4];
#pragma unroll
        for (int h2 = 0; h2 < 2; ++h2) {
            int b = bb + h2 * 16;
            const _Float16* gp = gx + (size_t)(t * 32 + b) * 4096 + dir * 2048 + j0 + jj;
#pragma unroll
            for (int g4 = 0; g4 < 4; ++g4) gxv[h2][g4] = (float)gp[g4 * 512];
        }
        // stage h_{s-1} (slot s&1) into LDS
        {
            const _Float16* src = hbuf + (size_t)(((s & 1) * 2 + dir) * 32) * 512;
#pragma unroll
            for (int i = 0; i < 8; ++i) {
                int c = tid + i * 256;
                int row = c >> 6, col = (c & 63) * 8;
                *(half8*)&h_s[row][col] = *(const half8*)(src + row * 512 + col);
            }
        }
        __syncthreads();
        // gates[j-slice] = h @ Whh_slice^T
        f32x4 acc0 = {0.f, 0.f, 0.f, 0.f}, acc1 = {0.f, 0.f, 0.f, 0.f};
#pragma unroll
        for (int ks = 0; ks < 16; ++ks) {
            half8 a0 = *(const half8*)&h_s[ln][ks * 32 + q * 8];
            half8 a1 = *(const half8*)&h_s[16 + ln][ks * 32 + q * 8];
            acc0 = __builtin_amdgcn_mfma_f32_16x16x32_f16(a0, wfrag[ks], acc0, 0, 0, 0);
            acc1 = __builtin_amdgcn_mfma_f32_16x16x32_f16(a1, wfrag[ks], acc1, 0, 0, 0);
        }
#pragma unroll
        for (int r = 0; r < 4; ++r) {
            gbuf[wave][q * 4 + r][ln] = acc0[r];
            gbuf[wave][16 + q * 4 + r][ln] = acc1[r];
        }
        __syncthreads();
        // elementwise LSTM cell for (b = bb, bb+16; j = jj)
#pragma unroll
        for (int h2 = 0; h2 < 2; ++h2) {
            int b = bb + h2 * 16;
            float iv = gbuf[0][b][jj] + gxv[h2][0];
            float fv = gbuf[1][b][jj] + gxv[h2][1];
            float gv = gbuf[2][b][jj] + gxv[h2][2];
            float ov = gbuf[3][b][jj] + gxv[h2][3];
            float cprev = h2 ? c1 : c0;
            float cn = sigf(fv) * cprev + sigf(iv) * tanhf_(gv);
            float hn = sigf(ov) * tanhf_(cn);
            if (h2) c1 = cn; else c0 = cn;
            _Float16 hh = (_Float16)hn;
            hbuf[(size_t)((((s + 1) & 1) * 2 + dir) * 32 + b) * 512 + j0 + jj] = hh;
            if (LAYER == 0) {
                hs_out[(size_t)(t * 32 + b) * 1024 + dir * 512 + j0 + jj] = hh;
            } else {
                out[(size_t)(b * 512 + t) * 1024 + dir * 512 + j0 + jj] = hn;
            }
            if (s == 511) {
                size_t off = (size_t)OUT_H_OFF + (size_t)((LAYER * 2 + dir) * 32 + b) * 512 + j0 + jj;
                out[off] = hn;
                out[off + OUT_HC_STRIDE] = cn;
            }
        }
        // device-scope grid barrier (64 blocks, all resident)
        if (s < 511) {
            __threadfence();
            __syncthreads();
            if (tid == 0) {
                __hip_atomic_fetch_add(bar, 1u, __ATOMIC_RELEASE, __HIP_MEMORY_SCOPE_AGENT);
                unsigned tgt = 64u * (unsigned)(s + 1);
                while (__hip_atomic_load(bar, __ATOMIC_ACQUIRE, __HIP_MEMORY_SCOPE_AGENT) < tgt) {
                    __builtin_amdgcn_s_sleep(1);
                }
            }
            __syncthreads();
            __threadfence();
        }
    }
}

extern "C" void kernel_launch(void* const* d_in, const int* in_sizes, int n_in,
                              void* d_out, int out_size, void* d_ws, size_t ws_size,
                              hipStream_t stream) {
    const float* X = (const float*)d_in[0];
    const float* WihF[2] = {(const float*)d_in[1], (const float*)d_in[9]};
    const float* WihR[2] = {(const float*)d_in[5], (const float*)d_in[13]};
    const float* WhhF[2] = {(const float*)d_in[2], (const float*)d_in[10]};
    const float* WhhR[2] = {(const float*)d_in[6], (const float*)d_in[14]};
    const float* bihF[2] = {(const float*)d_in[3], (const float*)d_in[11]};
    const float* bhhF[2] = {(const float*)d_in[4], (const float*)d_in[12]};
    const float* bihR[2] = {(const float*)d_in[7], (const float*)d_in[15]};
    const float* bhhR[2] = {(const float*)d_in[8], (const float*)d_in[16]};

    char* ws = (char*)d_ws;
    size_t off = 0;
    auto alloc = [&](size_t bytes) -> void* {
        void* p = ws + off;
        off += (bytes + 255) & ~(size_t)255;
        return p;
    };
    unsigned* bar   = (unsigned*)alloc(256);
    _Float16* hbuf0 = (_Float16*)alloc((size_t)2 * 2 * 32 * 512 * 2);   // 131072
    _Float16* hbuf1 = (_Float16*)alloc((size_t)2 * 2 * 32 * 512 * 2);
    _Float16* Xh    = (_Float16*)alloc((size_t)16384 * 512 * 2);
    _Float16* Wih0  = (_Float16*)alloc((size_t)4096 * 512 * 2);
    _Float16* Wih1  = (_Float16*)alloc((size_t)4096 * 1024 * 2);
    _Float16* Whh0  = (_Float16*)alloc((size_t)4096 * 512 * 2);
    _Float16* Whh1  = (_Float16*)alloc((size_t)4096 * 512 * 2);
    float*    bias0 = (float*)alloc(4096 * 4);
    float*    bias1 = (float*)alloc(4096 * 4);
    _Float16* hs0   = (_Float16*)alloc((size_t)16384 * 1024 * 2);
    _Float16* gx    = (_Float16*)alloc((size_t)16384 * 4096 * 2);
    if (off > ws_size) return;  // workspace too small: bail (bench will flag)

    // zero barrier counters + both h double-buffers (contiguous at ws start)
    hipMemsetAsync(d_ws, 0, 256 + 2 * 131072, stream);

    k_cast_x<<<8192, 256, 0, stream>>>(X, Xh);
    k_cast<<<1024, 256, 0, stream>>>(WihF[0], Wih0, 262144);
    k_cast<<<1024, 256, 0, stream>>>(WihR[0], Wih0 + (size_t)2048 * 512, 262144);
    k_cast<<<2048, 256, 0, stream>>>(WihF[1], Wih1, 524288);
    k_cast<<<2048, 256, 0, stream>>>(WihR[1], Wih1 + (size_t)2048 * 1024, 524288);
    k_cast<<<1024, 256, 0, stream>>>(WhhF[0], Whh0, 262144);
    k_cast<<<1024, 256, 0, stream>>>(WhhR[0], Whh0 + (size_t)2048 * 512, 262144);
    k_cast<<<1024, 256, 0, stream>>>(WhhF[1], Whh1, 262144);
    k_cast<<<1024, 256, 0, stream>>>(WhhR[1], Whh1 + (size_t)2048 * 512, 262144);
    k_bias<<<32, 256, 0, stream>>>(bihF[0], bhhF[0], bihR[0], bhhR[0],
                                   bihF[1], bhhF[1], bihR[1], bhhR[1], bias0, bias1);

    dim3 ggrid(32, 128);
    k_gemm<<<ggrid, 256, 0, stream>>>(Xh, Wih0, bias0, gx, 512);
    k_rec<0><<<64, 256, 0, stream>>>(gx, Whh0, hbuf0, hs0, (float*)d_out, bar);
    k_gemm<<<ggrid, 256, 0, stream>>>(hs0, Wih1, bias1, gx, 1024);
    k_rec<1><<<64, 256, 0, stream>>>(gx, Whh1, hbuf1, nullptr, (float*)d_out, bar + 16);
}

// Round 2
// 6360.551 us; speedup vs baseline: 2.2584x; 2.2584x over previous
//
#include <hip/hip_runtime.h>
#include <hip/hip_bf16.h>

typedef _Float16 half8 __attribute__((ext_vector_type(8)));
typedef float f32x4 __attribute__((ext_vector_type(4)));

#define OUT_H_OFF 16777216   // 32*512*1024
#define OUT_HC_STRIDE 65536  // 4*32*512

__device__ __forceinline__ float sigf(float x) { return 1.0f / (1.0f + __expf(-x)); }
__device__ __forceinline__ float tanhf_(float x) {
    float e = __expf(-2.0f * fabsf(x));
    float t = (1.0f - e) / (1.0f + e);
    return copysignf(t, x);
}

__device__ __forceinline__ unsigned pack2h(float a, float b) {
    union { unsigned u; _Float16 h[2]; } x;
    x.h[0] = (_Float16)a; x.h[1] = (_Float16)b;
    return x.u;
}
__device__ __forceinline__ float2 unpack2h(unsigned u) {
    union { unsigned v; _Float16 h[2]; } x; x.v = u;
    return make_float2((float)x.h[0], (float)x.h[1]);
}

// coherent (cross-XCD) 4B store: bypass L1+L2, land at coherent point
__device__ __forceinline__ void store_coh32(_Float16* p, unsigned v) {
    asm volatile("global_store_dword %0, %1, off sc0 sc1" :: "v"(p), "v"(v) : "memory");
}
// coherent 4B load (for barrier poll)
__device__ __forceinline__ unsigned load_coh32(const unsigned* p) {
    unsigned v;
    asm volatile("global_load_dword %0, %1, off sc0 sc1\n\t"
                 "s_waitcnt vmcnt(0)"
                 : "=v"(v) : "v"(p) : "memory");
    return v;
}

// ---------- prep kernels ----------
__global__ void k_cast(const float* __restrict__ s, _Float16* __restrict__ d, int n4) {
    int i = blockIdx.x * 256 + threadIdx.x;
    if (i < n4) {
        float4 v = ((const float4*)s)[i];
        _Float16* p = d + (size_t)i * 4;
        p[0] = (_Float16)v.x; p[1] = (_Float16)v.y; p[2] = (_Float16)v.z; p[3] = (_Float16)v.w;
    }
}

// X [32][512][512] fp32 -> Xh [t*32+b][512] fp16
__global__ void k_cast_x(const float* __restrict__ X, _Float16* __restrict__ Xh) {
    int i = blockIdx.x * 256 + threadIdx.x;
    int d = (i & 127) * 4;
    int rb = i >> 7;
    int b = rb & 31, t = rb >> 5;
    float4 v = *(const float4*)(X + ((size_t)b * 512 + t) * 512 + d);
    _Float16* p = Xh + (size_t)rb * 512 + d;
    p[0] = (_Float16)v.x; p[1] = (_Float16)v.y; p[2] = (_Float16)v.z; p[3] = (_Float16)v.w;
}

__global__ void k_bias(const float* __restrict__ a0, const float* __restrict__ b0,
                       const float* __restrict__ a1, const float* __restrict__ b1,
                       const float* __restrict__ a2, const float* __restrict__ b2,
                       const float* __restrict__ a3, const float* __restrict__ b3,
                       float* __restrict__ out0, float* __restrict__ out1) {
    int g = blockIdx.x * 256 + threadIdx.x;
    int j = g & 2047;
    int pair = g >> 11;
    const float *pa, *pb;
    switch (pair) {
        case 0: pa = a0; pb = b0; break;
        case 1: pa = a1; pb = b1; break;
        case 2: pa = a2; pb = b2; break;
        default: pa = a3; pb = b3; break;
    }
    float v = pa[j] + pb[j];
    if (g < 4096) out0[g] = v; else out1[g - 4096] = v;
}

// ---------- GEMM: C[M x 4096] = A[M x K] * W[4096 x K]^T + bias, fp16 in, fp16 out ----------
__global__ __launch_bounds__(256) void k_gemm(const _Float16* __restrict__ A,
                                              const _Float16* __restrict__ W,
                                              const float* __restrict__ bias,
                                              _Float16* __restrict__ C, int K) {
    __shared__ _Float16 As[128][72];
    __shared__ _Float16 Bs[128][72];
    const int tid = threadIdx.x;
    const int lane = tid & 63, wave = tid >> 6;
    const int ln = lane & 15, q = lane >> 4;
    const int wm = wave >> 1, wn = wave & 1;
    const int bm = blockIdx.y, bn = blockIdx.x;

    f32x4 acc[4][4] = {};
    const int kIters = K >> 6;
    for (int kt = 0; kt < kIters; ++kt) {
        const int k0 = kt << 6;
#pragma unroll
        for (int i = 0; i < 4; ++i) {
            int c = tid + i * 256;
            int row = c >> 3, kc = c & 7;
            *(half8*)&As[row][kc * 8] = *(const half8*)(A + (size_t)(bm * 128 + row) * K + k0 + kc * 8);
            *(half8*)&Bs[row][kc * 8] = *(const half8*)(W + (size_t)(bn * 128 + row) * K + k0 + kc * 8);
        }
        __syncthreads();
#pragma unroll
        for (int ks = 0; ks < 2; ++ks) {
            half8 a[4], b[4];
#pragma unroll
            for (int mi = 0; mi < 4; ++mi) a[mi] = *(const half8*)&As[wm * 64 + mi * 16 + ln][ks * 32 + q * 8];
#pragma unroll
            for (int ni = 0; ni < 4; ++ni) b[ni] = *(const half8*)&Bs[wn * 64 + ni * 16 + ln][ks * 32 + q * 8];
#pragma unroll
            for (int mi = 0; mi < 4; ++mi)
#pragma unroll
                for (int ni = 0; ni < 4; ++ni)
                    acc[mi][ni] = __builtin_amdgcn_mfma_f32_16x16x32_f16(a[mi], b[ni], acc[mi][ni], 0, 0, 0);
        }
        __syncthreads();
    }
#pragma unroll
    for (int ni = 0; ni < 4; ++ni) {
        int col = bn * 128 + wn * 64 + ni * 16 + ln;
        float bv = bias[col];
#pragma unroll
        for (int mi = 0; mi < 4; ++mi) {
            int row = bm * 128 + wm * 64 + mi * 16 + q * 4;
#pragma unroll
            for (int r = 0; r < 4; ++r) {
                C[(size_t)(row + r) * 4096 + col] = (_Float16)(acc[mi][ni][r] + bv);
            }
        }
    }
}

// ---------- persistent recurrence kernel ----------
// 64 blocks: 0..31 fwd, 32..63 rev. Block owns j-slice [j0,j0+16) of all 4 gates.
// h exchanged via double-buffered hbuf using coherent (sc0 sc1) loads/stores — NO cache
// fences anywhere in the loop. Per-direction relaxed atomic barrier.
template <int LAYER>
__global__ __launch_bounds__(256, 1) void k_rec(const _Float16* __restrict__ gx,    // [T*32][4096]
                                                const _Float16* __restrict__ Whh,   // [4096][512]
                                                _Float16* __restrict__ hbuf,        // [2][2][32][512] fp16
                                                _Float16* __restrict__ hs_out,      // L0: [T*32][1024]
                                                float* __restrict__ out,
                                                unsigned* __restrict__ bar) {
    __shared__ _Float16 h_s[32][520];
    __shared__ float gbuf[4][32][18];
    const int tid = threadIdx.x;
    const int lane = tid & 63, wave = tid >> 6;  // wave == gate (0:i 1:f 2:g 3:o)
    const int ln = lane & 15, q = lane >> 4;
    const int dir = blockIdx.x >> 5, jb = blockIdx.x & 31, j0 = jb * 16;
    unsigned* mybar = bar + dir * 32;

    // W_hh fragments for this wave's 16 gate-rows, held in VGPRs (zero per-step weight traffic)
    half8 wfrag[16];
    {
        const _Float16* wrow = Whh + (size_t)(dir * 2048 + wave * 512 + j0 + ln) * 512 + q * 8;
#pragma unroll
        for (int ks = 0; ks < 16; ++ks) wfrag[ks] = *(const half8*)(wrow + ks * 32);
    }

    const int b_el = tid >> 3, jp = tid & 7;    // elementwise/staging mapping
    float c0 = 0.f, c1 = 0.f;                   // cell state for (b_el, j0+2jp), (b_el, j0+2jp+1)

    // prefetch gx for first step (normal cached loads)
    unsigned gxn[4];
    {
        int t0 = dir ? 511 : 0;
        const _Float16* gp = gx + (size_t)(t0 * 32 + b_el) * 4096 + dir * 2048 + j0 + 2 * jp;
#pragma unroll
        for (int g = 0; g < 4; ++g) gxn[g] = *(const unsigned*)(gp + g * 512);
    }

    for (int s = 0; s < 512; ++s) {
        const int t = dir ? (511 - s) : s;

        // ---- stage h_{s} (slot s&1) into LDS via coherent 16B loads (128 B/thread) ----
        {
            const _Float16* src = hbuf + ((size_t)((s & 1) * 2 + dir) * 32 + b_el) * 512 + jp * 64;
            f32x4 f0, f1, f2, f3, f4, f5, f6, f7;
            asm volatile(
                "global_load_dwordx4 %0, %8, off sc0 sc1\n\t"
                "global_load_dwordx4 %1, %8, off offset:16 sc0 sc1\n\t"
                "global_load_dwordx4 %2, %8, off offset:32 sc0 sc1\n\t"
                "global_load_dwordx4 %3, %8, off offset:48 sc0 sc1\n\t"
                "global_load_dwordx4 %4, %8, off offset:64 sc0 sc1\n\t"
                "global_load_dwordx4 %5, %8, off offset:80 sc0 sc1\n\t"
                "global_load_dwordx4 %6, %8, off offset:96 sc0 sc1\n\t"
                "global_load_dwordx4 %7, %8, off offset:112 sc0 sc1\n\t"
                "s_waitcnt vmcnt(0)"
                : "=v"(f0), "=v"(f1), "=v"(f2), "=v"(f3),
                  "=v"(f4), "=v"(f5), "=v"(f6), "=v"(f7)
                : "v"(src)
                : "memory");
            _Float16* drow = &h_s[b_el][jp * 64];
            *(f32x4*)(drow + 0)  = f0;  *(f32x4*)(drow + 8)  = f1;
            *(f32x4*)(drow + 16) = f2;  *(f32x4*)(drow + 24) = f3;
            *(f32x4*)(drow + 32) = f4;  *(f32x4*)(drow + 40) = f5;
            *(f32x4*)(drow + 48) = f6;  *(f32x4*)(drow + 56) = f7;
        }
        __syncthreads();

        // ---- gates[j-slice] = h @ Whh_slice^T ----
        f32x4 acc0 = {0.f, 0.f, 0.f, 0.f}, acc1 = {0.f, 0.f, 0.f, 0.f};
#pragma unroll
        for (int ks = 0; ks < 16; ++ks) {
            half8 a0 = *(const half8*)&h_s[ln][ks * 32 + q * 8];
            half8 a1 = *(const half8*)&h_s[16 + ln][ks * 32 + q * 8];
            acc0 = __builtin_amdgcn_mfma_f32_16x16x32_f16(a0, wfrag[ks], acc0, 0, 0, 0);
            acc1 = __builtin_amdgcn_mfma_f32_16x16x32_f16(a1, wfrag[ks], acc1, 0, 0, 0);
        }
#pragma unroll
        for (int r = 0; r < 4; ++r) {
            gbuf[wave][q * 4 + r][ln] = acc0[r];
            gbuf[wave][16 + q * 4 + r][ln] = acc1[r];
        }
        __syncthreads();

        // ---- elementwise LSTM cell: (b_el, j = j0+2jp, j0+2jp+1) ----
        {
            float2 gi = *(float2*)&gbuf[0][b_el][2 * jp];
            float2 gf = *(float2*)&gbuf[1][b_el][2 * jp];
            float2 gg = *(float2*)&gbuf[2][b_el][2 * jp];
            float2 go = *(float2*)&gbuf[3][b_el][2 * jp];
            float2 xi = unpack2h(gxn[0]), xf = unpack2h(gxn[1]);
            float2 xg = unpack2h(gxn[2]), xo = unpack2h(gxn[3]);
            float i0 = gi.x + xi.x, i1 = gi.y + xi.y;
            float f0v = gf.x + xf.x, f1v = gf.y + xf.y;
            float g0 = gg.x + xg.x, g1 = gg.y + xg.y;
            float o0 = go.x + xo.x, o1 = go.y + xo.y;
            float cn0 = sigf(f0v) * c0 + sigf(i0) * tanhf_(g0);
            float cn1 = sigf(f1v) * c1 + sigf(i1) * tanhf_(g1);
            float hn0 = sigf(o0) * tanhf_(cn0);
            float hn1 = sigf(o1) * tanhf_(cn1);
            c0 = cn0; c1 = cn1;
            unsigned hp = pack2h(hn0, hn1);
            // coherent h store for next step
            store_coh32(hbuf + ((size_t)(((s + 1) & 1) * 2 + dir) * 32 + b_el) * 512 + j0 + 2 * jp, hp);
            // layer outputs (normal cached stores)
            if (LAYER == 0) {
                *(unsigned*)&hs_out[(size_t)(t * 32 + b_el) * 1024 + dir * 512 + j0 + 2 * jp] = hp;
            } else {
                *(float2*)&out[((size_t)b_el * 512 + t) * 1024 + dir * 512 + j0 + 2 * jp] = make_float2(hn0, hn1);
            }
            if (s == 511) {
                size_t off = (size_t)OUT_H_OFF + (size_t)((LAYER * 2 + dir) * 32 + b_el) * 512 + j0 + 2 * jp;
                *(float2*)&out[off] = make_float2(hn0, hn1);
                *(float2*)&out[off + OUT_HC_STRIDE] = make_float2(cn0, cn1);
            }
        }

        // ---- barrier: waitcnt + relaxed add + coherent poll (no cache fences) ----
        asm volatile("s_waitcnt vmcnt(0)" ::: "memory");
        __syncthreads();   // all waves' h stores retired before signaling

        if (s < 511) {
            // prefetch next step's gx while others arrive (cached loads, waited in poll)
            int tn = dir ? (510 - s) : (s + 1);
            const _Float16* gp = gx + (size_t)(tn * 32 + b_el) * 4096 + dir * 2048 + j0 + 2 * jp;
#pragma unroll
            for (int g = 0; g < 4; ++g) gxn[g] = *(const unsigned*)(gp + g * 512);

            if (tid == 0)
                __hip_atomic_fetch_add(mybar, 1u, __ATOMIC_RELAXED, __HIP_MEMORY_SCOPE_AGENT);
            const unsigned tgt = 32u * (unsigned)(s + 1);
            unsigned v = load_coh32(mybar);
            while (v < tgt) {
                __builtin_amdgcn_s_sleep(1);
                v = load_coh32(mybar);
            }
        }
    }
}

extern "C" void kernel_launch(void* const* d_in, const int* in_sizes, int n_in,
                              void* d_out, int out_size, void* d_ws, size_t ws_size,
                              hipStream_t stream) {
    const float* X = (const float*)d_in[0];
    const float* WihF[2] = {(const float*)d_in[1], (const float*)d_in[9]};
    const float* WihR[2] = {(const float*)d_in[5], (const float*)d_in[13]};
    const float* WhhF[2] = {(const float*)d_in[2], (const float*)d_in[10]};
    const float* WhhR[2] = {(const float*)d_in[6], (const float*)d_in[14]};
    const float* bihF[2] = {(const float*)d_in[3], (const float*)d_in[11]};
    const float* bhhF[2] = {(const float*)d_in[4], (const float*)d_in[12]};
    const float* bihR[2] = {(const float*)d_in[7], (const float*)d_in[15]};
    const float* bhhR[2] = {(const float*)d_in[8], (const float*)d_in[16]};

    char* ws = (char*)d_ws;
    size_t off = 0;
    auto alloc = [&](size_t bytes) -> void* {
        void* p = ws + off;
        off += (bytes + 255) & ~(size_t)255;
        return p;
    };
    unsigned* bar   = (unsigned*)alloc(512);                            // L0: [0],[32]; L1: [64],[96]
    _Float16* hbuf0 = (_Float16*)alloc((size_t)2 * 2 * 32 * 512 * 2);   // 131072 B
    _Float16* hbuf1 = (_Float16*)alloc((size_t)2 * 2 * 32 * 512 * 2);
    _Float16* Xh    = (_Float16*)alloc((size_t)16384 * 512 * 2);
    _Float16* Wih0  = (_Float16*)alloc((size_t)4096 * 512 * 2);
    _Float16* Wih1  = (_Float16*)alloc((size_t)4096 * 1024 * 2);
    _Float16* Whh0  = (_Float16*)alloc((size_t)4096 * 512 * 2);
    _Float16* Whh1  = (_Float16*)alloc((size_t)4096 * 512 * 2);
    float*    bias0 = (float*)alloc(4096 * 4);
    float*    bias1 = (float*)alloc(4096 * 4);
    _Float16* hs0   = (_Float16*)alloc((size_t)16384 * 1024 * 2);
    _Float16* gx    = (_Float16*)alloc((size_t)16384 * 4096 * 2);
    if (off > ws_size) return;

    // zero barrier counters + both h double-buffers (contiguous at ws start)
    hipMemsetAsync(d_ws, 0, 512 + 2 * 131072, stream);

    k_cast_x<<<8192, 256, 0, stream>>>(X, Xh);
    k_cast<<<1024, 256, 0, stream>>>(WihF[0], Wih0, 262144);
    k_cast<<<1024, 256, 0, stream>>>(WihR[0], Wih0 + (size_t)2048 * 512, 262144);
    k_cast<<<2048, 256, 0, stream>>>(WihF[1], Wih1, 524288);
    k_cast<<<2048, 256, 0, stream>>>(WihR[1], Wih1 + (size_t)2048 * 1024, 524288);
    k_cast<<<1024, 256, 0, stream>>>(WhhF[0], Whh0, 262144);
    k_cast<<<1024, 256, 0, stream>>>(WhhR[0], Whh0 + (size_t)2048 * 512, 262144);
    k_cast<<<1024, 256, 0, stream>>>(WhhF[1], Whh1, 262144);
    k_cast<<<1024, 256, 0, stream>>>(WhhR[1], Whh1 + (size_t)2048 * 512, 262144);
    k_bias<<<32, 256, 0, stream>>>(bihF[0], bhhF[0], bihR[0], bhhR[0],
                                   bihF[1], bhhF[1], bihR[1], bhhR[1], bias0, bias1);

    dim3 ggrid(32, 128);
    k_gemm<<<ggrid, 256, 0, stream>>>(Xh, Wih0, bias0, gx, 512);
    k_rec<0><<<64, 256, 0, stream>>>(gx, Whh0, hbuf0, hs0, (float*)d_out, bar);
    k_gemm<<<ggrid, 256, 0, stream>>>(hs0, Wih1, bias1, gx, 1024);
    k_rec<1><<<64, 256, 0, stream>>>(gx, Whh1, hbuf1, nullptr, (float*)d_out, bar + 64);
}

// Round 4
// 4350.074 us; speedup vs baseline: 3.3022x; 1.4622x over previous
//
#include <hip/hip_runtime.h>
#include <hip/hip_bf16.h>

typedef _Float16 half8 __attribute__((ext_vector_type(8)));
typedef float f32x4 __attribute__((ext_vector_type(4)));

#define OUT_H_OFF 16777216   // 32*512*1024
#define OUT_HC_STRIDE 65536  // 4*32*512

__device__ __forceinline__ float sigf(float x) { return 1.0f / (1.0f + __expf(-x)); }
__device__ __forceinline__ float tanhf_(float x) {
    float e = __expf(-2.0f * fabsf(x));
    float t = (1.0f - e) / (1.0f + e);
    return copysignf(t, x);
}

__device__ __forceinline__ unsigned pack2h(float a, float b) {
    union { unsigned u; _Float16 h[2]; } x;
    x.h[0] = (_Float16)a; x.h[1] = (_Float16)b;
    return x.u;
}
__device__ __forceinline__ float2 unpack2h(unsigned u) {
    union { unsigned v; _Float16 h[2]; } x; x.v = u;
    return make_float2((float)x.h[0], (float)x.h[1]);
}

// coherent (cross-XCD) ops: bypass L1+L2, land at / read from coherent point
__device__ __forceinline__ void store_coh32(void* p, unsigned v) {
    asm volatile("global_store_dword %0, %1, off sc0 sc1" :: "v"(p), "v"(v) : "memory");
}
__device__ __forceinline__ void store_coh64(void* p, unsigned long long v) {
    asm volatile("global_store_dwordx2 %0, %1, off sc0 sc1" :: "v"(p), "v"(v) : "memory");
}
__device__ __forceinline__ unsigned load_coh32(const unsigned* p) {
    unsigned v;
    asm volatile("global_load_dword %0, %1, off sc0 sc1\n\t"
                 "s_waitcnt vmcnt(0)"
                 : "=v"(v) : "v"(p) : "memory");
    return v;
}

// ---------- prep kernels ----------
__global__ void k_cast(const float* __restrict__ s, _Float16* __restrict__ d, int n4) {
    int i = blockIdx.x * 256 + threadIdx.x;
    if (i < n4) {
        float4 v = ((const float4*)s)[i];
        _Float16* p = d + (size_t)i * 4;
        p[0] = (_Float16)v.x; p[1] = (_Float16)v.y; p[2] = (_Float16)v.z; p[3] = (_Float16)v.w;
    }
}

// X [32][512][512] fp32 -> Xh [t*32+b][512] fp16
__global__ void k_cast_x(const float* __restrict__ X, _Float16* __restrict__ Xh) {
    int i = blockIdx.x * 256 + threadIdx.x;
    int d = (i & 127) * 4;
    int rb = i >> 7;
    int b = rb & 31, t = rb >> 5;
    float4 v = *(const float4*)(X + ((size_t)b * 512 + t) * 512 + d);
    _Float16* p = Xh + (size_t)rb * 512 + d;
    p[0] = (_Float16)v.x; p[1] = (_Float16)v.y; p[2] = (_Float16)v.z; p[3] = (_Float16)v.w;
}

__global__ void k_bias(const float* __restrict__ a0, const float* __restrict__ b0,
                       const float* __restrict__ a1, const float* __restrict__ b1,
                       const float* __restrict__ a2, const float* __restrict__ b2,
                       const float* __restrict__ a3, const float* __restrict__ b3,
                       float* __restrict__ out0, float* __restrict__ out1) {
    int g = blockIdx.x * 256 + threadIdx.x;
    int j = g & 2047;
    int pair = g >> 11;
    const float *pa, *pb;
    switch (pair) {
        case 0: pa = a0; pb = b0; break;
        case 1: pa = a1; pb = b1; break;
        case 2: pa = a2; pb = b2; break;
        default: pa = a3; pb = b3; break;
    }
    float v = pa[j] + pb[j];
    if (g < 4096) out0[g] = v; else out1[g - 4096] = v;
}

// hs [t*32+b][1024] fp16 -> out [b][t][1024] fp32 (row permutation, coalesced both sides)
__global__ void k_untile(const _Float16* __restrict__ hs, float* __restrict__ out) {
    int i = blockIdx.x * 256 + threadIdx.x;   // 4,194,304 threads
    int d4 = (i & 255) * 4;
    int rb = i >> 8;
    int b = rb & 31, t = rb >> 5;
    uint2 v = *(const uint2*)(hs + (size_t)rb * 1024 + d4);
    float2 x = unpack2h(v.x), y = unpack2h(v.y);
    *(float4*)(out + ((size_t)b * 512 + t) * 1024 + d4) = make_float4(x.x, x.y, y.x, y.y);
}

// ---------- GEMM: C[M x 4096] = A[M x K] * W[4096 x K]^T + bias, fp16 in, fp16 out ----------
__global__ __launch_bounds__(256) void k_gemm(const _Float16* __restrict__ A,
                                              const _Float16* __restrict__ W,
                                              const float* __restrict__ bias,
                                              _Float16* __restrict__ C, int K) {
    __shared__ _Float16 As[128][72];
    __shared__ _Float16 Bs[128][72];
    const int tid = threadIdx.x;
    const int lane = tid & 63, wave = tid >> 6;
    const int ln = lane & 15, q = lane >> 4;
    const int wm = wave >> 1, wn = wave & 1;
    const int bm = blockIdx.y, bn = blockIdx.x;

    f32x4 acc[4][4] = {};
    const int kIters = K >> 6;
    for (int kt = 0; kt < kIters; ++kt) {
        const int k0 = kt << 6;
#pragma unroll
        for (int i = 0; i < 4; ++i) {
            int c = tid + i * 256;
            int row = c >> 3, kc = c & 7;
            *(half8*)&As[row][kc * 8] = *(const half8*)(A + (size_t)(bm * 128 + row) * K + k0 + kc * 8);
            *(half8*)&Bs[row][kc * 8] = *(const half8*)(W + (size_t)(bn * 128 + row) * K + k0 + kc * 8);
        }
        __syncthreads();
#pragma unroll
        for (int ks = 0; ks < 2; ++ks) {
            half8 a[4], b[4];
#pragma unroll
            for (int mi = 0; mi < 4; ++mi) a[mi] = *(const half8*)&As[wm * 64 + mi * 16 + ln][ks * 32 + q * 8];
#pragma unroll
            for (int ni = 0; ni < 4; ++ni) b[ni] = *(const half8*)&Bs[wn * 64 + ni * 16 + ln][ks * 32 + q * 8];
#pragma unroll
            for (int mi = 0; mi < 4; ++mi)
#pragma unroll
                for (int ni = 0; ni < 4; ++ni)
                    acc[mi][ni] = __builtin_amdgcn_mfma_f32_16x16x32_f16(a[mi], b[ni], acc[mi][ni], 0, 0, 0);
        }
        __syncthreads();
    }
#pragma unroll
    for (int ni = 0; ni < 4; ++ni) {
        int col = bn * 128 + wn * 64 + ni * 16 + ln;
        float bv = bias[col];
#pragma unroll
        for (int mi = 0; mi < 4; ++mi) {
            int row = bm * 128 + wm * 64 + mi * 16 + q * 4;
#pragma unroll
            for (int r = 0; r < 4; ++r) {
                C[(size_t)(row + r) * 4096 + col] = (_Float16)(acc[mi][ni][r] + bv);
            }
        }
    }
}

// ---------- persistent recurrence kernel ----------
// 64 blocks x 128 threads: 0..31 fwd, 32..63 rev. Block owns j-slice [j0,j0+16).
// h lives in global hbuf in MFMA-fragment ("swizzled") order so staging is a LINEAR
// 32KB copy (conflict-free) and A-frag ds_read_b128 is lane-contiguous.
// 2 waves x 2 gates each halves LDS read volume. Exchange: coherent stores +
// per-block flag; readers spin on the 32 flags.
template <int LAYER>
__global__ __launch_bounds__(128, 1) void k_rec(const _Float16* __restrict__ gx,    // [T*32][4096]
                                                const _Float16* __restrict__ Whh,   // [4096][512]
                                                _Float16* __restrict__ hbuf,        // [2 slots][2 dirs][16384]
                                                _Float16* __restrict__ hs_out,      // [T*32][1024] fp16
                                                float* __restrict__ out,
                                                unsigned* __restrict__ flags) {     // [2 dirs][32]
    __shared__ _Float16 hswz[16384];          // 32 KB, linear copy of one hbuf slot-dir
    __shared__ float gbuf[4][32][20];
    const int tid = threadIdx.x;
    const int lane = tid & 63, wave = tid >> 6;        // 2 waves
    const int ln = lane & 15, q = lane >> 4;
    const int dir = blockIdx.x >> 5, jb = blockIdx.x & 31, j0 = jb * 16;
    unsigned* myflags = flags + dir * 32;

    // W_hh fragments: wave w handles gates 2w, 2w+1. 2 x 16 x half8 = 128 regs.
    half8 wfrag[2][16];
#pragma unroll
    for (int g2 = 0; g2 < 2; ++g2) {
        const _Float16* wrow = Whh + (size_t)(dir * 2048 + (wave * 2 + g2) * 512 + j0 + ln) * 512 + q * 8;
#pragma unroll
        for (int ks = 0; ks < 16; ++ks) wfrag[g2][ks] = *(const half8*)(wrow + ks * 32);
    }

    // elementwise mapping: thread -> (batch b_el, 4 consecutive j)
    const int b_el = tid >> 2, jq = tid & 3;
    const int kk = j0 + jq * 4;                         // global hidden index of first cell
    const int hswz_off = (((kk >> 5) * 2 + (b_el >> 4)) * 64 + ((kk >> 3) & 3) * 16 + (b_el & 15)) * 8 + (kk & 7);
    float c0 = 0.f, c1 = 0.f, c2 = 0.f, c3 = 0.f;

    // prefetch gx for first step
    uint2 gxn[4];
    {
        int t0 = dir ? 511 : 0;
        const _Float16* gp = gx + (size_t)(t0 * 32 + b_el) * 4096 + dir * 2048 + kk;
#pragma unroll
        for (int g = 0; g < 4; ++g) gxn[g] = *(const uint2*)(gp + g * 512);
    }

    for (int s = 0; s < 512; ++s) {
        const int t = dir ? (511 - s) : s;

        // ---- wait for all blocks' h of step s (flags monotonic) ----
        if (s > 0 && wave == 0) {
            const unsigned* fp = myflags + (lane & 31);
            unsigned v = load_coh32(fp);
            while (v < (unsigned)s) { __builtin_amdgcn_s_sleep(1); v = load_coh32(fp); }
        }
        __syncthreads();

        // ---- stage h (slot s&1, this dir): linear 32KB copy, 16 coherent dwordx4/thread ----
        // NOTE: outputs are EARLY-CLOBBER ("=&v") — destinations are written mid-block
        // while later loads still read the address inputs %16..%19; plain "=v" let the
        // allocator alias them (R3 crash).
        {
            const char* p0 = (const char*)(hbuf + ((size_t)((s & 1) * 2 + dir)) * 16384 + wave * 8192 + lane * 8);
            const char* p1 = p0 + 4096;
            const char* p2 = p0 + 8192;
            const char* p3 = p0 + 12288;
            f32x4 f0, f1, f2, f3, f4, f5, f6, f7, f8, f9, f10, f11, f12, f13, f14, f15;
            asm volatile(
                "global_load_dwordx4 %0, %16, off sc0 sc1\n\t"
                "global_load_dwordx4 %1, %16, off offset:1024 sc0 sc1\n\t"
                "global_load_dwordx4 %2, %16, off offset:2048 sc0 sc1\n\t"
                "global_load_dwordx4 %3, %16, off offset:3072 sc0 sc1\n\t"
                "global_load_dwordx4 %4, %17, off sc0 sc1\n\t"
                "global_load_dwordx4 %5, %17, off offset:1024 sc0 sc1\n\t"
                "global_load_dwordx4 %6, %17, off offset:2048 sc0 sc1\n\t"
                "global_load_dwordx4 %7, %17, off offset:3072 sc0 sc1\n\t"
                "global_load_dwordx4 %8, %18, off sc0 sc1\n\t"
                "global_load_dwordx4 %9, %18, off offset:1024 sc0 sc1\n\t"
                "global_load_dwordx4 %10, %18, off offset:2048 sc0 sc1\n\t"
                "global_load_dwordx4 %11, %18, off offset:3072 sc0 sc1\n\t"
                "global_load_dwordx4 %12, %19, off sc0 sc1\n\t"
                "global_load_dwordx4 %13, %19, off offset:1024 sc0 sc1\n\t"
                "global_load_dwordx4 %14, %19, off offset:2048 sc0 sc1\n\t"
                "global_load_dwordx4 %15, %19, off offset:3072 sc0 sc1\n\t"
                "s_waitcnt vmcnt(0)"
                : "=&v"(f0), "=&v"(f1), "=&v"(f2), "=&v"(f3), "=&v"(f4), "=&v"(f5), "=&v"(f6), "=&v"(f7),
                  "=&v"(f8), "=&v"(f9), "=&v"(f10), "=&v"(f11), "=&v"(f12), "=&v"(f13), "=&v"(f14), "=&v"(f15)
                : "v"(p0), "v"(p1), "v"(p2), "v"(p3)
                : "memory");
            _Float16* lb = &hswz[wave * 8192 + lane * 8];
            *(f32x4*)(lb + 0 * 512) = f0;   *(f32x4*)(lb + 1 * 512) = f1;
            *(f32x4*)(lb + 2 * 512) = f2;   *(f32x4*)(lb + 3 * 512) = f3;
            *(f32x4*)(lb + 4 * 512) = f4;   *(f32x4*)(lb + 5 * 512) = f5;
            *(f32x4*)(lb + 6 * 512) = f6;   *(f32x4*)(lb + 7 * 512) = f7;
            *(f32x4*)(lb + 8 * 512) = f8;   *(f32x4*)(lb + 9 * 512) = f9;
            *(f32x4*)(lb + 10 * 512) = f10; *(f32x4*)(lb + 11 * 512) = f11;
            *(f32x4*)(lb + 12 * 512) = f12; *(f32x4*)(lb + 13 * 512) = f13;
            *(f32x4*)(lb + 14 * 512) = f14; *(f32x4*)(lb + 15 * 512) = f15;
        }
        __syncthreads();

        // ---- gates: 2 gates/wave, both batch halves; conflict-free lane-contiguous reads ----
        {
            f32x4 a00 = {0,0,0,0}, a01 = {0,0,0,0}, a10 = {0,0,0,0}, a11 = {0,0,0,0};
            const _Float16* ap = &hswz[lane * 8];
#pragma unroll
            for (int ks = 0; ks < 16; ++ks) {
                half8 h0 = *(const half8*)(ap + ks * 1024);        // part 0 (b 0..15)
                half8 h1 = *(const half8*)(ap + ks * 1024 + 512);  // part 1 (b 16..31)
                a00 = __builtin_amdgcn_mfma_f32_16x16x32_f16(h0, wfrag[0][ks], a00, 0, 0, 0);
                a01 = __builtin_amdgcn_mfma_f32_16x16x32_f16(h1, wfrag[0][ks], a01, 0, 0, 0);
                a10 = __builtin_amdgcn_mfma_f32_16x16x32_f16(h0, wfrag[1][ks], a10, 0, 0, 0);
                a11 = __builtin_amdgcn_mfma_f32_16x16x32_f16(h1, wfrag[1][ks], a11, 0, 0, 0);
            }
            const int g0 = wave * 2, g1 = wave * 2 + 1;
#pragma unroll
            for (int r = 0; r < 4; ++r) {
                gbuf[g0][q * 4 + r][ln]      = a00[r];
                gbuf[g0][16 + q * 4 + r][ln] = a01[r];
                gbuf[g1][q * 4 + r][ln]      = a10[r];
                gbuf[g1][16 + q * 4 + r][ln] = a11[r];
            }
        }
        __syncthreads();

        // ---- elementwise LSTM cell: 4 cells per thread ----
        {
            float4 gi = *(float4*)&gbuf[0][b_el][jq * 4];
            float4 gf = *(float4*)&gbuf[1][b_el][jq * 4];
            float4 gg = *(float4*)&gbuf[2][b_el][jq * 4];
            float4 go = *(float4*)&gbuf[3][b_el][jq * 4];
            float2 xiA = unpack2h(gxn[0].x), xiB = unpack2h(gxn[0].y);
            float2 xfA = unpack2h(gxn[1].x), xfB = unpack2h(gxn[1].y);
            float2 xgA = unpack2h(gxn[2].x), xgB = unpack2h(gxn[2].y);
            float2 xoA = unpack2h(gxn[3].x), xoB = unpack2h(gxn[3].y);
            float cn0 = sigf(gf.x + xfA.x) * c0 + sigf(gi.x + xiA.x) * tanhf_(gg.x + xgA.x);
            float cn1 = sigf(gf.y + xfA.y) * c1 + sigf(gi.y + xiA.y) * tanhf_(gg.y + xgA.y);
            float cn2 = sigf(gf.z + xfB.x) * c2 + sigf(gi.z + xiB.x) * tanhf_(gg.z + xgB.x);
            float cn3 = sigf(gf.w + xfB.y) * c3 + sigf(gi.w + xiB.y) * tanhf_(gg.w + xgB.y);
            float hn0 = sigf(go.x + xoA.x) * tanhf_(cn0);
            float hn1 = sigf(go.y + xoA.y) * tanhf_(cn1);
            float hn2 = sigf(go.z + xoB.x) * tanhf_(cn2);
            float hn3 = sigf(go.w + xoB.y) * tanhf_(cn3);
            c0 = cn0; c1 = cn1; c2 = cn2; c3 = cn3;
            unsigned lo = pack2h(hn0, hn1), hi = pack2h(hn2, hn3);
            unsigned long long hp = ((unsigned long long)hi << 32) | lo;
            // coherent store into next slot (swizzled layout)
            store_coh64(hbuf + ((size_t)(((s + 1) & 1) * 2 + dir)) * 16384 + hswz_off, hp);
            // layer output (row-major, coalesced, cached)
            *(uint2*)(hs_out + (size_t)(t * 32 + b_el) * 1024 + dir * 512 + kk) = make_uint2(lo, hi);
            if (s == 511) {
                size_t fo = (size_t)OUT_H_OFF + (size_t)((LAYER * 2 + dir) * 32 + b_el) * 512 + kk;
                *(float4*)(out + fo) = make_float4(hn0, hn1, hn2, hn3);
                *(float4*)(out + fo + OUT_HC_STRIDE) = make_float4(cn0, cn1, cn2, cn3);
            }
        }

        // ---- publish: drain stores, then set own flag; prefetch next gx into poll window ----
        asm volatile("s_waitcnt vmcnt(0)" ::: "memory");
        __syncthreads();
        if (s < 511) {
            if (tid == 0) store_coh32(myflags + jb, (unsigned)(s + 1));
            int tn = dir ? (510 - s) : (s + 1);
            const _Float16* gp = gx + (size_t)(tn * 32 + b_el) * 4096 + dir * 2048 + kk;
#pragma unroll
            for (int g = 0; g < 4; ++g) gxn[g] = *(const uint2*)(gp + g * 512);
        }
    }
}

extern "C" void kernel_launch(void* const* d_in, const int* in_sizes, int n_in,
                              void* d_out, int out_size, void* d_ws, size_t ws_size,
                              hipStream_t stream) {
    const float* X = (const float*)d_in[0];
    const float* WihF[2] = {(const float*)d_in[1], (const float*)d_in[9]};
    const float* WihR[2] = {(const float*)d_in[5], (const float*)d_in[13]};
    const float* WhhF[2] = {(const float*)d_in[2], (const float*)d_in[10]};
    const float* WhhR[2] = {(const float*)d_in[6], (const float*)d_in[14]};
    const float* bihF[2] = {(const float*)d_in[3], (const float*)d_in[11]};
    const float* bhhF[2] = {(const float*)d_in[4], (const float*)d_in[12]};
    const float* bihR[2] = {(const float*)d_in[7], (const float*)d_in[15]};
    const float* bhhR[2] = {(const float*)d_in[8], (const float*)d_in[16]};

    char* ws = (char*)d_ws;
    size_t off = 0;
    auto alloc = [&](size_t bytes) -> void* {
        void* p = ws + off;
        off += (bytes + 255) & ~(size_t)255;
        return p;
    };
    unsigned* bar   = (unsigned*)alloc(512);                            // L0: [0..63], L1: [64..127]
    _Float16* hbuf0 = (_Float16*)alloc((size_t)2 * 2 * 16384 * 2);      // 131072 B
    _Float16* hbuf1 = (_Float16*)alloc((size_t)2 * 2 * 16384 * 2);
    _Float16* Xh    = (_Float16*)alloc((size_t)16384 * 512 * 2);
    _Float16* Wih0  = (_Float16*)alloc((size_t)4096 * 512 * 2);
    _Float16* Wih1  = (_Float16*)alloc((size_t)4096 * 1024 * 2);
    _Float16* Whh0  = (_Float16*)alloc((size_t)4096 * 512 * 2);
    _Float16* Whh1  = (_Float16*)alloc((size_t)4096 * 512 * 2);
    float*    bias0 = (float*)alloc(4096 * 4);
    float*    bias1 = (float*)alloc(4096 * 4);
    _Float16* hs0   = (_Float16*)alloc((size_t)16384 * 1024 * 2);       // reused by L1 output
    _Float16* gx    = (_Float16*)alloc((size_t)16384 * 4096 * 2);
    if (off > ws_size) return;

    // zero flags + both hbuf double-buffers (contiguous at ws start)
    hipMemsetAsync(d_ws, 0, 512 + 2 * 131072, stream);

    k_cast_x<<<8192, 256, 0, stream>>>(X, Xh);
    k_cast<<<1024, 256, 0, stream>>>(WihF[0], Wih0, 262144);
    k_cast<<<1024, 256, 0, stream>>>(WihR[0], Wih0 + (size_t)2048 * 512, 262144);
    k_cast<<<2048, 256, 0, stream>>>(WihF[1], Wih1, 524288);
    k_cast<<<2048, 256, 0, stream>>>(WihR[1], Wih1 + (size_t)2048 * 1024, 524288);
    k_cast<<<1024, 256, 0, stream>>>(WhhF[0], Whh0, 262144);
    k_cast<<<1024, 256, 0, stream>>>(WhhR[0], Whh0 + (size_t)2048 * 512, 262144);
    k_cast<<<1024, 256, 0, stream>>>(WhhF[1], Whh1, 262144);
    k_cast<<<1024, 256, 0, stream>>>(WhhR[1], Whh1 + (size_t)2048 * 512, 262144);
    k_bias<<<32, 256, 0, stream>>>(bihF[0], bhhF[0], bihR[0], bhhR[0],
                                   bihF[1], bhhF[1], bihR[1], bhhR[1], bias0, bias1);

    dim3 ggrid(32, 128);
    k_gemm<<<ggrid, 256, 0, stream>>>(Xh, Wih0, bias0, gx, 512);
    k_rec<0><<<64, 128, 0, stream>>>(gx, Whh0, hbuf0, hs0, (float*)d_out, bar);
    k_gemm<<<ggrid, 256, 0, stream>>>(hs0, Wih1, bias1, gx, 1024);
    k_rec<1><<<64, 128, 0, stream>>>(gx, Whh1, hbuf1, hs0, (float*)d_out, bar + 64);
    k_untile<<<16384, 256, 0, stream>>>(hs0, (float*)d_out);
}